// Round 8
// baseline (340.364 us; speedup 1.0000x reference)
//
#include <hip/hip_runtime.h>
#include <stdint.h>

#define E_N 600000
#define N_N 100000

typedef short short8   __attribute__((ext_vector_type(8)));
typedef short short8a  __attribute__((ext_vector_type(8), may_alias));
typedef float floatx4  __attribute__((ext_vector_type(4)));
typedef float floatx2  __attribute__((ext_vector_type(2)));
typedef float floatx4a __attribute__((ext_vector_type(4), may_alias));
typedef float floatx8a __attribute__((ext_vector_type(8), may_alias));
typedef unsigned int uintx2  __attribute__((ext_vector_type(2)));
typedef unsigned int uintx2a __attribute__((ext_vector_type(2), may_alias));
typedef unsigned int uintx4a __attribute__((ext_vector_type(4), may_alias));
typedef __bf16 bf16x4 __attribute__((ext_vector_type(4)));
typedef __bf16 bf16x8 __attribute__((ext_vector_type(8)));

static __device__ __forceinline__ unsigned short f2bf(float f){
  unsigned u = __builtin_bit_cast(unsigned, f);
  unsigned rnd = 0x7fffu + ((u >> 16) & 1u);
  return (unsigned short)((u + rnd) >> 16);
}
static __device__ __forceinline__ unsigned pk2(float a, float b){
  floatx2 f; f[0] = a; f[1] = b;
  typedef __bf16 bf16x2 __attribute__((ext_vector_type(2)));
  return __builtin_bit_cast(unsigned, __builtin_convertvector(f, bf16x2));
}

// ---- prep: weights -> bf16, swizzled, W1 in three 32KB k-windows (k=128 each).
// window layout (u16): win*16384 + (c*64 + ((k'>>1) ^ ((c&7)<<2)))*2 + (k&1)
__global__ void prep_weights(const float* __restrict__ W1, const float* __restrict__ W2,
                             unsigned short* __restrict__ w1s, unsigned short* __restrict__ w2s){
  int i = blockIdx.x * 256 + threadIdx.x;
  if (i < 384 * 128){
    int c = i / 384, k = i - c * 384;
    int p = k >> 7, kp = k & 127;
    int dw = c * 64 + ((kp >> 1) ^ ((c & 7) << 2));
    w1s[p * 16384 + dw * 2 + (k & 1)] = f2bf(W1[k * 128 + c]);
  } else {
    int j = i - 384 * 128;            // grid sized exactly: j < 16384
    int c = j >> 7, k = j & 127;
    int dw = c * 64 + ((k >> 1) ^ ((c & 7) << 2));
    w2s[dw * 2 + (k & 1)] = f2bf(W2[k * 128 + c]);
  }
}

// ---- prep: copy nfeat -> output[1]; nfeat f32 -> bf16 in ws
__global__ void prep_nfeat(const float* __restrict__ nf,
                           unsigned* __restrict__ nfbu,
                           float* __restrict__ out2){
  const int total = N_N * 128 / 4;
  int stride = gridDim.x * blockDim.x;
  for (int i = blockIdx.x * blockDim.x + threadIdx.x; i < total; i += stride){
    float4 v = reinterpret_cast<const float4*>(nf)[i];
    reinterpret_cast<float4*>(out2)[i] = v;
    nfbu[2 * i]     = pk2(v.x, v.y);
    nfbu[2 * i + 1] = pk2(v.z, v.w);
  }
}

static __device__ __forceinline__ void glds16(void* lds, const void* g){
  __builtin_amdgcn_global_load_lds((const __attribute__((address_space(1))) unsigned int*)g,
                                   (__attribute__((address_space(3))) unsigned int*)lds,
                                   16, 0, 0);
}

// ---- fused, operand-swapped: h^T = W1^T X^T ; y^T = W2^T h^T
// 512 thr = 8 waves, 32 edges/wave (2 e-frags), W in a 32KB LDS window (3 phases + W2).
// LDS = 66KB -> 2 blocks/CU. acc1 retires BEFORE the W2 restage: e2=0 -> tile,
// e2=1 -> 16 packed VGPRs (hpk), written to the tile after GEMM2 pass 0.
__global__ __launch_bounds__(512, 4) void fused_edge(
    const float* __restrict__ efeat,
    const int* __restrict__ src_idx, const int* __restrict__ dst_idx,
    const unsigned short* __restrict__ nfb,
    const unsigned short* __restrict__ w1s, const unsigned short* __restrict__ w2s,
    const float* __restrict__ b1, const float* __restrict__ b2,
    const float* __restrict__ lns, const float* __restrict__ lnb,
    float* __restrict__ out)
{
  // [0, 32768)       : W window (swizzled bf16): W1 k-win 0,1,2 then W2
  // [32768, 65536)   : per-wave h tile, 4 KB each ([16 edge][64 dw], swizzled)
  // [65536, 67584)   : biases: b1 | b2 | ln_scale | ln_bias (128 f32 each)
  __shared__ __align__(16) unsigned char smem[67584];
  unsigned int* wlds  = (unsigned int*)smem;
  float*        cmisc = (float*)(smem + 65536);

  const int tid  = threadIdx.x;
  const int w    = tid >> 6;
  const int lane = tid & 63;
  const int r    = lane & 15;     // A row (chan) / B col (edge)
  const int g    = lane >> 4;     // k-group; D row = 4g+q
  const int sw8  = (r & 7) << 2;  // dword XOR swizzle

  unsigned int* tile = (unsigned int*)(smem + 32768 + w * 4096);

  auto stageW = [&](const unsigned short* src){
    #pragma unroll
    for (int rnd = 0; rnd < 4; ++rnd){
      int off = rnd * 8192 + tid * 16;
      glds16(smem + off, (const unsigned char*)src + off);
    }
  };

  stageW(w1s);                       // window 0
  cmisc[tid] = tid < 128 ? b1[tid] : tid < 256 ? b2[tid - 128]
             : tid < 384 ? lns[tid - 256] : lnb[tid - 384];

  const int eb = blockIdx.x * 256 + w * 32;

  int er[2];
  #pragma unroll
  for (int e2 = 0; e2 < 2; ++e2){
    int e = eb + 16 * e2 + r;
    er[e2] = e < E_N ? e : (E_N - 1);
  }
  int gidx[2][2];
  #pragma unroll
  for (int e2 = 0; e2 < 2; ++e2){
    int si = src_idx[er[e2]];
    int di = dst_idx[er[e2]];
    si = si < 0 ? 0 : (si >= N_N ? N_N - 1 : si);
    di = di < 0 ? 0 : (di >= N_N ? N_N - 1 : di);
    gidx[0][e2] = si;
    gidx[1][e2] = di;
  }

  __syncthreads();   // window 0 + cmisc ready

  auto loadX_f32 = [&](const float* p) -> short8 {
    floatx8a f = *reinterpret_cast<const floatx8a*>(p);
    return __builtin_bit_cast(short8, __builtin_convertvector(f, bf16x8));
  };
  // W frag from current window: row 16m+r, local k = k4*32 + 8g .. +7
  auto loadWL = [&](int m, int k4) -> short8 {
    uintx4a v = *reinterpret_cast<const uintx4a*>(
        &wlds[(16 * m + r) * 64 + ((k4 * 16 + 4 * g) ^ sw8)]);
    return __builtin_bit_cast(short8, v);
  };

  // ---- GEMM1: acc1[e2][mi] = h[chan 16mi+4g+q][edge 16e2+r], 3 staged k-windows
  floatx4 acc1[2][8];
  #pragma unroll
  for (int e2 = 0; e2 < 2; ++e2)
    #pragma unroll
    for (int mi = 0; mi < 8; ++mi)
      acc1[e2][mi] = (floatx4){0.f, 0.f, 0.f, 0.f};

  // silu+pack one (e2, mi) quad from acc1
  auto siluPack = [&](int e2, int mi) -> uintx2 {
    floatx4 bb = *reinterpret_cast<const floatx4a*>(&cmisc[16 * mi + 4 * g]);
    floatx4 vv;
    #pragma unroll
    for (int q = 0; q < 4; ++q){
      float xx = acc1[e2][mi][q] + bb[q];
      vv[q] = xx * __builtin_amdgcn_rcpf(1.f + __expf(-xx));   // silu
    }
    return __builtin_bit_cast(uintx2, __builtin_convertvector(vv, bf16x4));
  };

  uintx2 hpk[8];   // packed h for e2=1, held in regs across GEMM2 pass 0

  #pragma unroll
  for (int p = 0; p < 3; ++p){
    #pragma unroll
    for (int k4 = 0; k4 < 4; ++k4){
      const int kf = p * 4 + k4;
      short8 x[2];
      #pragma unroll
      for (int e2 = 0; e2 < 2; ++e2){
        if (kf < 4)
          x[e2] = loadX_f32(efeat + (size_t)er[e2] * 128 + kf * 32 + 8 * g);
        else if (kf < 8)
          x[e2] = *reinterpret_cast<const short8a*>(nfb + (size_t)gidx[0][e2] * 128 + (kf - 4) * 32 + 8 * g);
        else
          x[e2] = *reinterpret_cast<const short8a*>(nfb + (size_t)gidx[1][e2] * 128 + (kf - 8) * 32 + 8 * g);
      }
      #pragma unroll
      for (int mi = 0; mi < 8; ++mi){
        short8 wf = loadWL(mi, k4);
        acc1[0][mi] = __builtin_amdgcn_mfma_f32_16x16x32_bf16(wf, x[0], acc1[0][mi], 0, 0, 0);
        acc1[1][mi] = __builtin_amdgcn_mfma_f32_16x16x32_bf16(wf, x[1], acc1[1][mi], 0, 0, 0);
      }
    }
    // retire acc1 entirely before the restage barrier (tile is wave-private):
    // e2=0 -> tile now; e2=1 -> registers (tile holds only 16 edge rows!)
    if (p == 2){
      #pragma unroll
      for (int mi = 0; mi < 8; ++mi)
        *reinterpret_cast<uintx2a*>(&tile[r * 64 + ((8 * mi + 2 * g) ^ sw8)]) = siluPack(0, mi);
      #pragma unroll
      for (int mi = 0; mi < 8; ++mi)
        hpk[mi] = siluPack(1, mi);
    }
    __syncthreads();                                  // all waves done with window p
    if (p < 2) stageW(w1s + (p + 1) * 16384);         // next W1 window
    else       stageW(w2s);                           // W2
    __syncthreads();                                  // window staged
  }

  // ---- per e-frag: GEMM2 + LN epilogue (only acc2 + hpk live)
  #pragma unroll
  for (int e2 = 0; e2 < 2; ++e2){
    if (e2 == 1){
      // wave-private handoff: overwrite tile with stashed h for e2=1.
      // DS pipe is in-order per wave; may_alias types keep compiler ordering.
      #pragma unroll
      for (int mi = 0; mi < 8; ++mi)
        *reinterpret_cast<uintx2a*>(&tile[r * 64 + ((8 * mi + 2 * g) ^ sw8)]) = hpk[mi];
    }

    floatx4 acc2[8];
    #pragma unroll
    for (int mo = 0; mo < 8; ++mo)
      acc2[mo] = (floatx4){0.f, 0.f, 0.f, 0.f};

    #pragma unroll
    for (int ks = 0; ks < 4; ++ks){
      uintx4a hv = *reinterpret_cast<const uintx4a*>(&tile[r * 64 + ((ks * 16 + 4 * g) ^ sw8)]);
      short8 hb = __builtin_bit_cast(short8, hv);
      #pragma unroll
      for (int mo = 0; mo < 8; ++mo){
        short8 wf = loadWL(mo, ks);
        acc2[mo] = __builtin_amdgcn_mfma_f32_16x16x32_bf16(wf, hb, acc2[mo], 0, 0, 0);
      }
    }

    float s1 = 0.f, s2 = 0.f;
    #pragma unroll
    for (int mo = 0; mo < 8; ++mo){
      floatx4 bb = *reinterpret_cast<const floatx4a*>(&cmisc[128 + 16 * mo + 4 * g]);
      #pragma unroll
      for (int q = 0; q < 4; ++q){
        float v = acc2[mo][q] + bb[q];
        s1 += v; s2 += v * v;
      }
    }
    s1 += __shfl_xor(s1, 16); s2 += __shfl_xor(s2, 16);
    s1 += __shfl_xor(s1, 32); s2 += __shfl_xor(s2, 32);

    float mu   = s1 * (1.f / 128.f);
    float var  = s2 * (1.f / 128.f) - mu * mu;
    var = var > 0.f ? var : 0.f;
    float rstd = __builtin_amdgcn_rsqf(var + 1e-5f);

    int e = eb + 16 * e2 + r;
    if (e < E_N){
      const float* ef = efeat + (size_t)e * 128;
      float*       op = out   + (size_t)e * 128;
      #pragma unroll
      for (int mo = 0; mo < 8; ++mo){
        int c = 16 * mo + 4 * g;
        floatx4 bb = *reinterpret_cast<const floatx4a*>(&cmisc[128 + c]);
        floatx4 ls = *reinterpret_cast<const floatx4a*>(&cmisc[256 + c]);
        floatx4 lb = *reinterpret_cast<const floatx4a*>(&cmisc[384 + c]);
        floatx4 e4 = *reinterpret_cast<const floatx4a*>(ef + c);
        floatx4 o4;
        #pragma unroll
        for (int q = 0; q < 4; ++q)
          o4[q] = (acc2[mo][q] + bb[q] - mu) * rstd * ls[q] + lb[q] + e4[q];
        *reinterpret_cast<floatx4a*>(op + c) = o4;
      }
    }
  }
}

extern "C" void kernel_launch(void* const* d_in, const int* in_sizes, int n_in,
                              void* d_out, int out_size, void* d_ws, size_t ws_size,
                              hipStream_t stream){
  const float* efeat = (const float*)d_in[0];
  const float* nfeat = (const float*)d_in[1];
  const int*   srci  = (const int*)d_in[2];
  const int*   dsti  = (const int*)d_in[3];
  const float* W1    = (const float*)d_in[4];
  const float* b1    = (const float*)d_in[5];
  const float* W2    = (const float*)d_in[6];
  const float* b2    = (const float*)d_in[7];
  const float* lns   = (const float*)d_in[8];
  const float* lnb   = (const float*)d_in[9];
  float* out = (float*)d_out;

  char* ws = (char*)d_ws;
  unsigned short* w1s = (unsigned short*)ws;               // 98,304 B (3 swizzled windows)
  unsigned short* w2s = (unsigned short*)(ws + 98304);     // 32,768 B (swizzled)
  unsigned short* nfb = (unsigned short*)(ws + 131072);    // 25,600,000 B

  prep_weights<<<(384 * 128 + 128 * 128) / 256, 256, 0, stream>>>(W1, W2, w1s, w2s);
  prep_nfeat<<<2048, 256, 0, stream>>>(nfeat, (unsigned*)nfb, out + (size_t)E_N * 128);

  int blocks = (E_N + 255) / 256;   // 2344
  fused_edge<<<blocks, 512, 0, stream>>>(efeat, srci, dsti, nfb, w1s, w2s,
                                         b1, b2, lns, lnb, out);
}

// Round 9
// 262.730 us; speedup vs baseline: 1.2955x; 1.2955x over previous
//
#include <hip/hip_runtime.h>
#include <stdint.h>

#define E_N 600000
#define N_N 100000

typedef short short8   __attribute__((ext_vector_type(8)));
typedef short short8a  __attribute__((ext_vector_type(8), may_alias));
typedef float floatx4  __attribute__((ext_vector_type(4)));
typedef float floatx2  __attribute__((ext_vector_type(2)));
typedef float floatx4a __attribute__((ext_vector_type(4), may_alias));
typedef float floatx8a __attribute__((ext_vector_type(8), may_alias));
typedef unsigned int uintx2  __attribute__((ext_vector_type(2)));
typedef unsigned int uintx2a __attribute__((ext_vector_type(2), may_alias));
typedef unsigned int uintx4a __attribute__((ext_vector_type(4), may_alias));
typedef __bf16 bf16x4 __attribute__((ext_vector_type(4)));
typedef __bf16 bf16x8 __attribute__((ext_vector_type(8)));

static __device__ __forceinline__ unsigned short f2bf(float f){
  unsigned u = __builtin_bit_cast(unsigned, f);
  unsigned rnd = 0x7fffu + ((u >> 16) & 1u);
  return (unsigned short)((u + rnd) >> 16);
}
static __device__ __forceinline__ unsigned pk2(float a, float b){
  floatx2 f; f[0] = a; f[1] = b;
  typedef __bf16 bf16x2 __attribute__((ext_vector_type(2)));
  return __builtin_bit_cast(unsigned, __builtin_convertvector(f, bf16x2));
}

// ---- prep: weights -> bf16, swizzled, W1 in three 32KB k-windows (k=128 each).
// window layout (u16): win*16384 + (c*64 + ((k'>>1) ^ ((c&7)<<2)))*2 + (k&1)
__global__ void prep_weights(const float* __restrict__ W1, const float* __restrict__ W2,
                             unsigned short* __restrict__ w1s, unsigned short* __restrict__ w2s){
  int i = blockIdx.x * 256 + threadIdx.x;
  if (i < 384 * 128){
    int c = i / 384, k = i - c * 384;
    int p = k >> 7, kp = k & 127;
    int dw = c * 64 + ((kp >> 1) ^ ((c & 7) << 2));
    w1s[p * 16384 + dw * 2 + (k & 1)] = f2bf(W1[k * 128 + c]);
  } else {
    int j = i - 384 * 128;            // grid sized exactly: j < 16384
    int c = j >> 7, k = j & 127;
    int dw = c * 64 + ((k >> 1) ^ ((c & 7) << 2));
    w2s[dw * 2 + (k & 1)] = f2bf(W2[k * 128 + c]);
  }
}

// ---- prep: copy nfeat -> output[1]; nfeat f32 -> bf16 in ws
__global__ void prep_nfeat(const float* __restrict__ nf,
                           unsigned* __restrict__ nfbu,
                           float* __restrict__ out2){
  const int total = N_N * 128 / 4;
  int stride = gridDim.x * blockDim.x;
  for (int i = blockIdx.x * blockDim.x + threadIdx.x; i < total; i += stride){
    float4 v = reinterpret_cast<const float4*>(nf)[i];
    reinterpret_cast<float4*>(out2)[i] = v;
    nfbu[2 * i]     = pk2(v.x, v.y);
    nfbu[2 * i + 1] = pk2(v.z, v.w);
  }
}

static __device__ __forceinline__ void glds16(void* lds, const void* g){
  __builtin_amdgcn_global_load_lds((const __attribute__((address_space(1))) unsigned int*)g,
                                   (__attribute__((address_space(3))) unsigned int*)lds,
                                   16, 0, 0);
}

// ---- fused, operand-swapped: h^T = W1^T X^T ; y^T = W2^T h^T
// 512 thr = 8 waves, **16 edges/wave** (1 e-frag), W in a 32KB LDS window.
// LDS = 66KB -> 2 blocks/CU; regs fit 128 -> 4 waves/SIMD genuinely resident.
__global__ __launch_bounds__(512, 4) void fused_edge(
    const float* __restrict__ efeat,
    const int* __restrict__ src_idx, const int* __restrict__ dst_idx,
    const unsigned short* __restrict__ nfb,
    const unsigned short* __restrict__ w1s, const unsigned short* __restrict__ w2s,
    const float* __restrict__ b1, const float* __restrict__ b2,
    const float* __restrict__ lns, const float* __restrict__ lnb,
    float* __restrict__ out)
{
  // [0, 32768)       : W window (swizzled bf16): W1 k-win 0,1,2 then W2
  // [32768, 65536)   : per-wave h tile, 4 KB each ([16 edge][64 dw], swizzled)
  // [65536, 67584)   : biases: b1 | b2 | ln_scale | ln_bias (128 f32 each)
  __shared__ __align__(16) unsigned char smem[67584];
  unsigned int* wlds  = (unsigned int*)smem;
  float*        cmisc = (float*)(smem + 65536);

  const int tid  = threadIdx.x;
  const int w    = tid >> 6;
  const int lane = tid & 63;
  const int r    = lane & 15;     // A row (chan) / B col (edge)
  const int g    = lane >> 4;     // k-group; D row = 4g+q
  const int sw8  = (r & 7) << 2;  // dword XOR swizzle

  unsigned int* tile = (unsigned int*)(smem + 32768 + w * 4096);

  auto stageW = [&](const unsigned short* src){
    #pragma unroll
    for (int rnd = 0; rnd < 4; ++rnd){
      int off = rnd * 8192 + tid * 16;
      glds16(smem + off, (const unsigned char*)src + off);
    }
  };

  stageW(w1s);                       // window 0
  cmisc[tid] = tid < 128 ? b1[tid] : tid < 256 ? b2[tid - 128]
             : tid < 384 ? lns[tid - 256] : lnb[tid - 384];

  const int eb = blockIdx.x * 128 + w * 16;

  int e0 = eb + r;
  const int er = e0 < E_N ? e0 : (E_N - 1);
  int si = src_idx[er];
  int di = dst_idx[er];
  si = si < 0 ? 0 : (si >= N_N ? N_N - 1 : si);
  di = di < 0 ? 0 : (di >= N_N ? N_N - 1 : di);

  __syncthreads();   // window 0 + cmisc ready

  auto loadX_f32 = [&](const float* p) -> short8 {
    floatx8a f = *reinterpret_cast<const floatx8a*>(p);
    return __builtin_bit_cast(short8, __builtin_convertvector(f, bf16x8));
  };
  // W frag from current window: row 16m+r, local k = k4*32 + 8g .. +7
  auto loadWL = [&](int m, int k4) -> short8 {
    uintx4a v = *reinterpret_cast<const uintx4a*>(
        &wlds[(16 * m + r) * 64 + ((k4 * 16 + 4 * g) ^ sw8)]);
    return __builtin_bit_cast(short8, v);
  };

  // ---- GEMM1: acc1[mi] = h[chan 16mi+4g+q][edge r], 3 staged k-windows
  floatx4 acc1[8];
  #pragma unroll
  for (int mi = 0; mi < 8; ++mi)
    acc1[mi] = (floatx4){0.f, 0.f, 0.f, 0.f};

  #pragma unroll
  for (int p = 0; p < 3; ++p){
    #pragma unroll
    for (int k4 = 0; k4 < 4; ++k4){
      const int kf = p * 4 + k4;
      short8 x;
      if (kf < 4)
        x = loadX_f32(efeat + (size_t)er * 128 + kf * 32 + 8 * g);
      else if (kf < 8)
        x = *reinterpret_cast<const short8a*>(nfb + (size_t)si * 128 + (kf - 4) * 32 + 8 * g);
      else
        x = *reinterpret_cast<const short8a*>(nfb + (size_t)di * 128 + (kf - 8) * 32 + 8 * g);
      #pragma unroll
      for (int mi = 0; mi < 8; ++mi){
        short8 wf = loadWL(mi, k4);
        acc1[mi] = __builtin_amdgcn_mfma_f32_16x16x32_bf16(wf, x, acc1[mi], 0, 0, 0);
      }
    }
    // retire acc1 (wave-private tile: no sync needed) before the restage barrier
    if (p == 2){
      #pragma unroll
      for (int mi = 0; mi < 8; ++mi){
        floatx4 bb = *reinterpret_cast<const floatx4a*>(&cmisc[16 * mi + 4 * g]);
        floatx4 vv;
        #pragma unroll
        for (int q = 0; q < 4; ++q){
          float xx = acc1[mi][q] + bb[q];
          vv[q] = xx * __builtin_amdgcn_rcpf(1.f + __expf(-xx));   // silu
        }
        uintx2 pk = __builtin_bit_cast(uintx2, __builtin_convertvector(vv, bf16x4));
        *reinterpret_cast<uintx2a*>(&tile[r * 64 + ((8 * mi + 2 * g) ^ sw8)]) = pk;
      }
    }
    __syncthreads();                                  // all waves done with window p
    if (p < 2) stageW(w1s + (p + 1) * 16384);         // next W1 window
    else       stageW(w2s);                           // W2
    __syncthreads();                                  // window staged
  }

  // ---- GEMM2 + LN epilogue (acc1 dead; only acc2 live)
  floatx4 acc2[8];
  #pragma unroll
  for (int mo = 0; mo < 8; ++mo)
    acc2[mo] = (floatx4){0.f, 0.f, 0.f, 0.f};

  #pragma unroll
  for (int ks = 0; ks < 4; ++ks){
    uintx4a hv = *reinterpret_cast<const uintx4a*>(&tile[r * 64 + ((ks * 16 + 4 * g) ^ sw8)]);
    short8 hb = __builtin_bit_cast(short8, hv);
    #pragma unroll
    for (int mo = 0; mo < 8; ++mo){
      short8 wf = loadWL(mo, ks);
      acc2[mo] = __builtin_amdgcn_mfma_f32_16x16x32_bf16(wf, hb, acc2[mo], 0, 0, 0);
    }
  }

  float s1 = 0.f, s2 = 0.f;
  #pragma unroll
  for (int mo = 0; mo < 8; ++mo){
    floatx4 bb = *reinterpret_cast<const floatx4a*>(&cmisc[128 + 16 * mo + 4 * g]);
    #pragma unroll
    for (int q = 0; q < 4; ++q){
      float v = acc2[mo][q] + bb[q];
      s1 += v; s2 += v * v;
    }
  }
  s1 += __shfl_xor(s1, 16); s2 += __shfl_xor(s2, 16);
  s1 += __shfl_xor(s1, 32); s2 += __shfl_xor(s2, 32);

  float mu   = s1 * (1.f / 128.f);
  float var  = s2 * (1.f / 128.f) - mu * mu;
  var = var > 0.f ? var : 0.f;
  float rstd = __builtin_amdgcn_rsqf(var + 1e-5f);

  if (e0 < E_N){
    const float* ef = efeat + (size_t)e0 * 128;
    float*       op = out   + (size_t)e0 * 128;
    #pragma unroll
    for (int mo = 0; mo < 8; ++mo){
      int c = 16 * mo + 4 * g;
      floatx4 bb = *reinterpret_cast<const floatx4a*>(&cmisc[128 + c]);
      floatx4 ls = *reinterpret_cast<const floatx4a*>(&cmisc[256 + c]);
      floatx4 lb = *reinterpret_cast<const floatx4a*>(&cmisc[384 + c]);
      floatx4 e4 = *reinterpret_cast<const floatx4a*>(ef + c);
      floatx4 o4;
      #pragma unroll
      for (int q = 0; q < 4; ++q)
        o4[q] = (acc2[mo][q] + bb[q] - mu) * rstd * ls[q] + lb[q] + e4[q];
      *reinterpret_cast<floatx4a*>(op + c) = o4;
    }
  }
}

extern "C" void kernel_launch(void* const* d_in, const int* in_sizes, int n_in,
                              void* d_out, int out_size, void* d_ws, size_t ws_size,
                              hipStream_t stream){
  const float* efeat = (const float*)d_in[0];
  const float* nfeat = (const float*)d_in[1];
  const int*   srci  = (const int*)d_in[2];
  const int*   dsti  = (const int*)d_in[3];
  const float* W1    = (const float*)d_in[4];
  const float* b1    = (const float*)d_in[5];
  const float* W2    = (const float*)d_in[6];
  const float* b2    = (const float*)d_in[7];
  const float* lns   = (const float*)d_in[8];
  const float* lnb   = (const float*)d_in[9];
  float* out = (float*)d_out;

  char* ws = (char*)d_ws;
  unsigned short* w1s = (unsigned short*)ws;               // 98,304 B (3 swizzled windows)
  unsigned short* w2s = (unsigned short*)(ws + 98304);     // 32,768 B (swizzled)
  unsigned short* nfb = (unsigned short*)(ws + 131072);    // 25,600,000 B

  prep_weights<<<(384 * 128 + 128 * 128) / 256, 256, 0, stream>>>(W1, W2, w1s, w2s);
  prep_nfeat<<<2048, 256, 0, stream>>>(nfeat, (unsigned*)nfb, out + (size_t)E_N * 128);

  int blocks = (E_N + 127) / 128;   // 4688
  fused_edge<<<blocks, 512, 0, stream>>>(efeat, srci, dsti, nfb, w1s, w2s,
                                         b1, b2, lns, lnb, out);
}

// Round 10
// 249.220 us; speedup vs baseline: 1.3657x; 1.0542x over previous
//
#include <hip/hip_runtime.h>
#include <stdint.h>

#define E_N 600000
#define N_N 100000

typedef short short8   __attribute__((ext_vector_type(8)));
typedef short short8a  __attribute__((ext_vector_type(8), may_alias));
typedef float floatx4  __attribute__((ext_vector_type(4)));
typedef float floatx2  __attribute__((ext_vector_type(2)));
typedef float floatx4a __attribute__((ext_vector_type(4), may_alias));
typedef float floatx8a __attribute__((ext_vector_type(8), may_alias));
typedef unsigned int uintx2  __attribute__((ext_vector_type(2)));
typedef unsigned int uintx2a __attribute__((ext_vector_type(2), may_alias));
typedef unsigned int uintx4a __attribute__((ext_vector_type(4), may_alias));
typedef __bf16 bf16x4 __attribute__((ext_vector_type(4)));
typedef __bf16 bf16x8 __attribute__((ext_vector_type(8)));

static __device__ __forceinline__ unsigned short f2bf(float f){
  unsigned u = __builtin_bit_cast(unsigned, f);
  unsigned rnd = 0x7fffu + ((u >> 16) & 1u);
  return (unsigned short)((u + rnd) >> 16);
}
static __device__ __forceinline__ unsigned pk2(float a, float b){
  floatx2 f; f[0] = a; f[1] = b;
  typedef __bf16 bf16x2 __attribute__((ext_vector_type(2)));
  return __builtin_bit_cast(unsigned, __builtin_convertvector(f, bf16x2));
}

// ---- prep: weights -> bf16, swizzled, W1 in three 32KB k-windows (k=128 each).
// window layout (u16): win*16384 + (c*64 + ((k'>>1) ^ ((c&7)<<2)))*2 + (k&1)
__global__ void prep_weights(const float* __restrict__ W1, const float* __restrict__ W2,
                             unsigned short* __restrict__ w1s, unsigned short* __restrict__ w2s){
  int i = blockIdx.x * 256 + threadIdx.x;
  if (i < 384 * 128){
    int c = i / 384, k = i - c * 384;
    int p = k >> 7, kp = k & 127;
    int dw = c * 64 + ((kp >> 1) ^ ((c & 7) << 2));
    w1s[p * 16384 + dw * 2 + (k & 1)] = f2bf(W1[k * 128 + c]);
  } else {
    int j = i - 384 * 128;            // grid sized exactly: j < 16384
    int c = j >> 7, k = j & 127;
    int dw = c * 64 + ((k >> 1) ^ ((c & 7) << 2));
    w2s[dw * 2 + (k & 1)] = f2bf(W2[k * 128 + c]);
  }
}

// ---- prep: copy nfeat -> output[1]; nfeat f32 -> bf16 in ws
__global__ void prep_nfeat(const float* __restrict__ nf,
                           unsigned* __restrict__ nfbu,
                           float* __restrict__ out2){
  const int total = N_N * 128 / 4;
  int stride = gridDim.x * blockDim.x;
  for (int i = blockIdx.x * blockDim.x + threadIdx.x; i < total; i += stride){
    float4 v = reinterpret_cast<const float4*>(nf)[i];
    reinterpret_cast<float4*>(out2)[i] = v;
    nfbu[2 * i]     = pk2(v.x, v.y);
    nfbu[2 * i + 1] = pk2(v.z, v.w);
  }
}

static __device__ __forceinline__ void glds16(void* lds, const void* g){
  __builtin_amdgcn_global_load_lds((const __attribute__((address_space(1))) unsigned int*)g,
                                   (__attribute__((address_space(3))) unsigned int*)lds,
                                   16, 0, 0);
}

// ---- fused, operand-swapped: h^T = W1^T X^T ; y^T = W2^T h^T
// 512 thr = 8 waves, 16 edges/wave, W in a 32KB LDS window (3 W1 phases + W2).
// ALL X/gather frags prefetched to 48 VGPRs BEFORE the first barrier: GEMM1
// phases are pure LDS+MFMA (no VMEM latency inside the barrier-fenced phases).
__global__ __launch_bounds__(512, 4) void fused_edge(
    const float* __restrict__ efeat,
    const int* __restrict__ src_idx, const int* __restrict__ dst_idx,
    const unsigned short* __restrict__ nfb,
    const unsigned short* __restrict__ w1s, const unsigned short* __restrict__ w2s,
    const float* __restrict__ b1, const float* __restrict__ b2,
    const float* __restrict__ lns, const float* __restrict__ lnb,
    float* __restrict__ out)
{
  // [0, 32768)       : W window (swizzled bf16): W1 k-win 0,1,2 then W2
  // [32768, 65536)   : per-wave h tile, 4 KB each ([16 edge][64 dw], swizzled)
  // [65536, 67584)   : biases: b1 | b2 | ln_scale | ln_bias (128 f32 each)
  __shared__ __align__(16) unsigned char smem[67584];
  unsigned int* wlds  = (unsigned int*)smem;
  float*        cmisc = (float*)(smem + 65536);

  const int tid  = threadIdx.x;
  const int w    = tid >> 6;
  const int lane = tid & 63;
  const int r    = lane & 15;     // A row (chan) / B col (edge)
  const int g    = lane >> 4;     // k-group; D row = 4g+q
  const int sw8  = (r & 7) << 2;  // dword XOR swizzle

  unsigned int* tile = (unsigned int*)(smem + 32768 + w * 4096);

  auto stageW = [&](const unsigned short* src){
    #pragma unroll
    for (int rnd = 0; rnd < 4; ++rnd){
      int off = rnd * 8192 + tid * 16;
      glds16(smem + off, (const unsigned char*)src + off);
    }
  };

  stageW(w1s);                       // window 0
  cmisc[tid] = tid < 128 ? b1[tid] : tid < 256 ? b2[tid - 128]
             : tid < 384 ? lns[tid - 256] : lnb[tid - 384];

  const int eb = blockIdx.x * 128 + w * 16;

  int e0 = eb + r;
  const int er = e0 < E_N ? e0 : (E_N - 1);
  int si = src_idx[er];
  int di = dst_idx[er];
  si = si < 0 ? 0 : (si >= N_N ? N_N - 1 : si);
  di = di < 0 ? 0 : (di >= N_N ? N_N - 1 : di);

  auto loadX_f32 = [&](const float* p) -> short8 {
    floatx8a f = *reinterpret_cast<const floatx8a*>(p);
    return __builtin_bit_cast(short8, __builtin_convertvector(f, bf16x8));
  };

  // ---- prefetch the ENTIRE per-wave X working set into registers (48 VGPRs)
  // before the first barrier: 16 VMEM instrs overlap the window-0 staging.
  short8 xf[12];
  #pragma unroll
  for (int kf = 0; kf < 4; ++kf)
    xf[kf] = loadX_f32(efeat + (size_t)er * 128 + kf * 32 + 8 * g);
  #pragma unroll
  for (int kf = 0; kf < 4; ++kf)
    xf[4 + kf] = *reinterpret_cast<const short8a*>(nfb + (size_t)si * 128 + kf * 32 + 8 * g);
  #pragma unroll
  for (int kf = 0; kf < 4; ++kf)
    xf[8 + kf] = *reinterpret_cast<const short8a*>(nfb + (size_t)di * 128 + kf * 32 + 8 * g);

  __syncthreads();   // window 0 + cmisc ready

  // W frag from current window: row 16m+r, local k = k4*32 + 8g .. +7
  auto loadWL = [&](int m, int k4) -> short8 {
    uintx4a v = *reinterpret_cast<const uintx4a*>(
        &wlds[(16 * m + r) * 64 + ((k4 * 16 + 4 * g) ^ sw8)]);
    return __builtin_bit_cast(short8, v);
  };

  // ---- GEMM1: acc1[mi] = h[chan 16mi+4g+q][edge r], 3 staged k-windows
  floatx4 acc1[8];
  #pragma unroll
  for (int mi = 0; mi < 8; ++mi)
    acc1[mi] = (floatx4){0.f, 0.f, 0.f, 0.f};

  #pragma unroll
  for (int p = 0; p < 3; ++p){
    #pragma unroll
    for (int k4 = 0; k4 < 4; ++k4){
      short8 x = xf[p * 4 + k4];
      #pragma unroll
      for (int mi = 0; mi < 8; ++mi){
        short8 wf = loadWL(mi, k4);
        acc1[mi] = __builtin_amdgcn_mfma_f32_16x16x32_bf16(wf, x, acc1[mi], 0, 0, 0);
      }
    }
    // retire acc1 (wave-private tile: no sync needed) before the restage barrier
    if (p == 2){
      #pragma unroll
      for (int mi = 0; mi < 8; ++mi){
        floatx4 bb = *reinterpret_cast<const floatx4a*>(&cmisc[16 * mi + 4 * g]);
        floatx4 vv;
        #pragma unroll
        for (int q = 0; q < 4; ++q){
          float xx = acc1[mi][q] + bb[q];
          vv[q] = xx * __builtin_amdgcn_rcpf(1.f + __expf(-xx));   // silu
        }
        uintx2 pk = __builtin_bit_cast(uintx2, __builtin_convertvector(vv, bf16x4));
        *reinterpret_cast<uintx2a*>(&tile[r * 64 + ((8 * mi + 2 * g) ^ sw8)]) = pk;
      }
    }
    __syncthreads();                                  // all waves done with window p
    if (p < 2) stageW(w1s + (p + 1) * 16384);         // next W1 window
    else       stageW(w2s);                           // W2
    __syncthreads();                                  // window staged
  }

  // ---- GEMM2 + LN epilogue (acc1 dead; only acc2 live)
  floatx4 acc2[8];
  #pragma unroll
  for (int mo = 0; mo < 8; ++mo)
    acc2[mo] = (floatx4){0.f, 0.f, 0.f, 0.f};

  #pragma unroll
  for (int ks = 0; ks < 4; ++ks){
    uintx4a hv = *reinterpret_cast<const uintx4a*>(&tile[r * 64 + ((ks * 16 + 4 * g) ^ sw8)]);
    short8 hb = __builtin_bit_cast(short8, hv);
    #pragma unroll
    for (int mo = 0; mo < 8; ++mo){
      short8 wf = loadWL(mo, ks);
      acc2[mo] = __builtin_amdgcn_mfma_f32_16x16x32_bf16(wf, hb, acc2[mo], 0, 0, 0);
    }
  }

  // prefetch residual BEFORE the LN reduce (er is always a valid row)
  const float* ef = efeat + (size_t)er * 128;
  floatx4 e4v[8];
  #pragma unroll
  for (int mo = 0; mo < 8; ++mo)
    e4v[mo] = *reinterpret_cast<const floatx4a*>(ef + 16 * mo + 4 * g);

  float s1 = 0.f, s2 = 0.f;
  #pragma unroll
  for (int mo = 0; mo < 8; ++mo){
    floatx4 bb = *reinterpret_cast<const floatx4a*>(&cmisc[128 + 16 * mo + 4 * g]);
    #pragma unroll
    for (int q = 0; q < 4; ++q){
      float v = acc2[mo][q] + bb[q];
      s1 += v; s2 += v * v;
    }
  }
  s1 += __shfl_xor(s1, 16); s2 += __shfl_xor(s2, 16);
  s1 += __shfl_xor(s1, 32); s2 += __shfl_xor(s2, 32);

  float mu   = s1 * (1.f / 128.f);
  float var  = s2 * (1.f / 128.f) - mu * mu;
  var = var > 0.f ? var : 0.f;
  float rstd = __builtin_amdgcn_rsqf(var + 1e-5f);

  if (e0 < E_N){
    float* op = out + (size_t)e0 * 128;
    #pragma unroll
    for (int mo = 0; mo < 8; ++mo){
      int c = 16 * mo + 4 * g;
      floatx4 bb = *reinterpret_cast<const floatx4a*>(&cmisc[128 + c]);
      floatx4 ls = *reinterpret_cast<const floatx4a*>(&cmisc[256 + c]);
      floatx4 lb = *reinterpret_cast<const floatx4a*>(&cmisc[384 + c]);
      floatx4 o4;
      #pragma unroll
      for (int q = 0; q < 4; ++q)
        o4[q] = (acc2[mo][q] + bb[q] - mu) * rstd * ls[q] + lb[q] + e4v[mo][q];
      *reinterpret_cast<floatx4a*>(op + c) = o4;
    }
  }
}

extern "C" void kernel_launch(void* const* d_in, const int* in_sizes, int n_in,
                              void* d_out, int out_size, void* d_ws, size_t ws_size,
                              hipStream_t stream){
  const float* efeat = (const float*)d_in[0];
  const float* nfeat = (const float*)d_in[1];
  const int*   srci  = (const int*)d_in[2];
  const int*   dsti  = (const int*)d_in[3];
  const float* W1    = (const float*)d_in[4];
  const float* b1    = (const float*)d_in[5];
  const float* W2    = (const float*)d_in[6];
  const float* b2    = (const float*)d_in[7];
  const float* lns   = (const float*)d_in[8];
  const float* lnb   = (const float*)d_in[9];
  float* out = (float*)d_out;

  char* ws = (char*)d_ws;
  unsigned short* w1s = (unsigned short*)ws;               // 98,304 B (3 swizzled windows)
  unsigned short* w2s = (unsigned short*)(ws + 98304);     // 32,768 B (swizzled)
  unsigned short* nfb = (unsigned short*)(ws + 131072);    // 25,600,000 B

  prep_weights<<<(384 * 128 + 128 * 128) / 256, 256, 0, stream>>>(W1, W2, w1s, w2s);
  prep_nfeat<<<2048, 256, 0, stream>>>(nfeat, (unsigned*)nfb, out + (size_t)E_N * 128);

  int blocks = (E_N + 127) / 128;   // 4688
  fused_edge<<<blocks, 512, 0, stream>>>(efeat, srci, dsti, nfb, w1s, w2s,
                                         b1, b2, lns, lnb, out);
}

// Round 11
// 234.187 us; speedup vs baseline: 1.4534x; 1.0642x over previous
//
#include <hip/hip_runtime.h>
#include <stdint.h>

#define E_N 600000
#define N_N 100000

typedef short short8   __attribute__((ext_vector_type(8)));
typedef short short8a  __attribute__((ext_vector_type(8), may_alias));
typedef float floatx4  __attribute__((ext_vector_type(4)));
typedef float floatx2  __attribute__((ext_vector_type(2)));
typedef float floatx4a __attribute__((ext_vector_type(4), may_alias));
typedef float floatx8a __attribute__((ext_vector_type(8), may_alias));
typedef unsigned int uintx2  __attribute__((ext_vector_type(2)));
typedef unsigned int uintx2a __attribute__((ext_vector_type(2), may_alias));
typedef unsigned int uintx4  __attribute__((ext_vector_type(4)));
typedef unsigned int uintx4a __attribute__((ext_vector_type(4), may_alias));
typedef __bf16 bf16x4 __attribute__((ext_vector_type(4)));
typedef __bf16 bf16x8 __attribute__((ext_vector_type(8)));

static __device__ __forceinline__ unsigned short f2bf(float f){
  unsigned u = __builtin_bit_cast(unsigned, f);
  unsigned rnd = 0x7fffu + ((u >> 16) & 1u);
  return (unsigned short)((u + rnd) >> 16);
}
static __device__ __forceinline__ unsigned pk2(float a, float b){
  floatx2 f; f[0] = a; f[1] = b;
  typedef __bf16 bf16x2 __attribute__((ext_vector_type(2)));
  return __builtin_bit_cast(unsigned, __builtin_convertvector(f, bf16x2));
}

// ---- prep: weights -> bf16, swizzled, EIGHT 16KB k-windows (k=64 each):
// windows 0..5 = W1 (k 0..383), windows 6..7 = W2 (k 0..127).
// u16 index: win*8192 + (c*32 + ((k'>>1) ^ ((c&7)<<2)))*2 + (k'&1)
__global__ void prep_weights(const float* __restrict__ W1, const float* __restrict__ W2,
                             unsigned short* __restrict__ wall){
  int i = blockIdx.x * 256 + threadIdx.x;
  if (i < 384 * 128){
    int c = i / 384, k = i - c * 384;
    int win = k >> 6, kp = k & 63;
    wall[win * 8192 + (c * 32 + ((kp >> 1) ^ ((c & 7) << 2))) * 2 + (kp & 1)]
      = f2bf(W1[k * 128 + c]);
  } else {
    int j = i - 384 * 128;            // grid sized exactly: j < 16384
    int c = j >> 7, k = j & 127;
    int win = 6 + (k >> 6), kp = k & 63;
    wall[win * 8192 + (c * 32 + ((kp >> 1) ^ ((c & 7) << 2))) * 2 + (kp & 1)]
      = f2bf(W2[k * 128 + c]);
  }
}

// ---- prep: copy nfeat -> output[1]; nfeat f32 -> bf16 in ws
__global__ void prep_nfeat(const float* __restrict__ nf,
                           unsigned* __restrict__ nfbu,
                           float* __restrict__ out2){
  const int total = N_N * 128 / 4;
  int stride = gridDim.x * blockDim.x;
  for (int i = blockIdx.x * blockDim.x + threadIdx.x; i < total; i += stride){
    float4 v = reinterpret_cast<const float4*>(nf)[i];
    reinterpret_cast<float4*>(out2)[i] = v;
    nfbu[2 * i]     = pk2(v.x, v.y);
    nfbu[2 * i + 1] = pk2(v.z, v.w);
  }
}

static __device__ __forceinline__ void glds16(void* lds, const void* g){
  __builtin_amdgcn_global_load_lds((const __attribute__((address_space(1))) unsigned int*)g,
                                   (__attribute__((address_space(3))) unsigned int*)lds,
                                   16, 0, 0);
}

// ---- fused, operand-swapped: h^T = W1^T X^T ; y^T = W2^T h^T
// 256 thr = 4 waves, 16 edges/wave. Eight 16KB W windows, DOUBLE-BUFFERED:
// stage t+1 issued at the start of compute-t, one barrier per window, no
// stage-wait bubble. LDS = 50KB -> 3 blocks/CU (3 independent phase streams).
// Residual comes from xf[0..3] (bf16 efeat) via the wave-private tile: efeat
// is read from HBM exactly once.
__global__ __launch_bounds__(256, 3) void fused_edge(
    const float* __restrict__ efeat,
    const int* __restrict__ src_idx, const int* __restrict__ dst_idx,
    const unsigned short* __restrict__ nfb,
    const unsigned short* __restrict__ wall,
    const float* __restrict__ b1, const float* __restrict__ b2,
    const float* __restrict__ lns, const float* __restrict__ lnb,
    float* __restrict__ out)
{
  // [0, 32768)      : two 16KB W buffers (double-buffered windows)
  // [32768, 49152)  : per-wave h/residual tile, 4 KB each ([16 edge][64 dw], swizzled)
  // [49152, 51200)  : biases: b1 | b2 | ln_scale | ln_bias (128 f32 each)
  __shared__ __align__(16) unsigned char smem[51200];
  unsigned int* wbuf  = (unsigned int*)smem;
  float*        cmisc = (float*)(smem + 49152);

  const int tid  = threadIdx.x;
  const int w    = tid >> 6;
  const int lane = tid & 63;
  const int r    = lane & 15;     // A row (chan) / B col (edge)
  const int g    = lane >> 4;     // k-group; D row = 4g+q
  const int sw8  = (r & 7) << 2;  // dword XOR swizzle

  unsigned int* tile = (unsigned int*)(smem + 32768 + w * 4096);

  auto stageW = [&](int b, int win){
    const unsigned char* src = (const unsigned char*)wall + win * 16384;
    #pragma unroll
    for (int rnd = 0; rnd < 4; ++rnd){
      int off = rnd * 4096 + tid * 16;
      glds16(smem + b * 16384 + off, src + off);
    }
  };

  stageW(0, 0);                      // window 0 -> buffer 0
  cmisc[tid]       = tid < 128 ? b1[tid]  : b2[tid - 128];
  cmisc[tid + 256] = tid < 128 ? lns[tid] : lnb[tid - 128];

  const int eb = blockIdx.x * 64 + w * 16;
  const int e0 = eb + r;            // grid is exact: e0 < E_N always
  int si = src_idx[e0];
  int di = dst_idx[e0];
  si = si < 0 ? 0 : (si >= N_N ? N_N - 1 : si);
  di = di < 0 ? 0 : (di >= N_N ? N_N - 1 : di);

  auto loadX_f32 = [&](const float* p) -> short8 {
    floatx8a f = *reinterpret_cast<const floatx8a*>(p);
    return __builtin_bit_cast(short8, __builtin_convertvector(f, bf16x8));
  };

  // prefetch the ENTIRE per-wave X working set (48 VGPRs) before the barrier;
  // xf[0..3] (bf16 efeat) stays live to the end as the residual source.
  short8 xf[12];
  #pragma unroll
  for (int kf = 0; kf < 4; ++kf)
    xf[kf] = loadX_f32(efeat + (size_t)e0 * 128 + kf * 32 + 8 * g);
  #pragma unroll
  for (int kf = 0; kf < 4; ++kf)
    xf[4 + kf] = *reinterpret_cast<const short8a*>(nfb + (size_t)si * 128 + kf * 32 + 8 * g);
  #pragma unroll
  for (int kf = 0; kf < 4; ++kf)
    xf[8 + kf] = *reinterpret_cast<const short8a*>(nfb + (size_t)di * 128 + kf * 32 + 8 * g);

  __syncthreads();   // window 0 + cmisc ready

  // W frag from buffer b: row 16m+r, local k = k2*32 + 8g .. +7 (row = 32 dwords)
  auto loadWL = [&](int b, int m, int k2) -> short8 {
    uintx4a v = *reinterpret_cast<const uintx4a*>(
        &wbuf[b * 4096 + (16 * m + r) * 32 + ((k2 * 16 + 4 * g) ^ sw8)]);
    return __builtin_bit_cast(short8, v);
  };

  // ---- GEMM1: 6 double-buffered W1 windows (k=64 each)
  floatx4 acc1[8];
  #pragma unroll
  for (int mi = 0; mi < 8; ++mi)
    acc1[mi] = (floatx4){0.f, 0.f, 0.f, 0.f};

  #pragma unroll
  for (int t = 0; t < 6; ++t){
    stageW((t + 1) & 1, t + 1);      // async: next window into the other buffer
    const int b = t & 1;
    #pragma unroll
    for (int k2 = 0; k2 < 2; ++k2){
      short8 x = xf[2 * t + k2];
      #pragma unroll
      for (int mi = 0; mi < 8; ++mi){
        short8 wf = loadWL(b, mi, k2);
        acc1[mi] = __builtin_amdgcn_mfma_f32_16x16x32_bf16(wf, x, acc1[mi], 0, 0, 0);
      }
    }
    if (t == 5){
      // retire acc1: +b1, silu, pack bf16, wave-private tile (no sync needed)
      #pragma unroll
      for (int mi = 0; mi < 8; ++mi){
        floatx4 bb = *reinterpret_cast<const floatx4a*>(&cmisc[16 * mi + 4 * g]);
        floatx4 vv;
        #pragma unroll
        for (int q = 0; q < 4; ++q){
          float xx = acc1[mi][q] + bb[q];
          vv[q] = xx * __builtin_amdgcn_rcpf(1.f + __expf(-xx));   // silu
        }
        uintx2 pk = __builtin_bit_cast(uintx2, __builtin_convertvector(vv, bf16x4));
        *reinterpret_cast<uintx2a*>(&tile[r * 64 + ((8 * mi + 2 * g) ^ sw8)]) = pk;
      }
    }
    __syncthreads();                 // done reading buf b; buf b^1 staged
  }

  // ---- GEMM2: 2 double-buffered W2 windows (ks 0,1 | 2,3)
  floatx4 acc2[8];
  #pragma unroll
  for (int mo = 0; mo < 8; ++mo)
    acc2[mo] = (floatx4){0.f, 0.f, 0.f, 0.f};

  #pragma unroll
  for (int t = 6; t < 8; ++t){
    if (t < 7) stageW((t + 1) & 1, t + 1);
    const int b = t & 1;
    #pragma unroll
    for (int k2 = 0; k2 < 2; ++k2){
      const int ks = 2 * (t - 6) + k2;
      uintx4a hv = *reinterpret_cast<const uintx4a*>(&tile[r * 64 + ((ks * 16 + 4 * g) ^ sw8)]);
      short8 hb = __builtin_bit_cast(short8, hv);
      #pragma unroll
      for (int mo = 0; mo < 8; ++mo){
        short8 wf = loadWL(b, mo, k2);
        acc2[mo] = __builtin_amdgcn_mfma_f32_16x16x32_bf16(wf, hb, acc2[mo], 0, 0, 0);
      }
    }
    if (t < 7) __syncthreads();
  }

  // ---- residual handoff: overwrite tile with bf16 efeat (all tile reads done;
  // wave-private, in-order DS pipe, same may_alias access type preserves order)
  #pragma unroll
  for (int kf = 0; kf < 4; ++kf)
    *reinterpret_cast<uintx4a*>(&tile[r * 64 + ((16 * kf + 4 * g) ^ sw8)]) =
        __builtin_bit_cast(uintx4, xf[kf]);

  // ---- +b2, LN (2 shuffles), *scale+bias, +efeat(bf16 from tile), store
  float s1 = 0.f, s2 = 0.f;
  #pragma unroll
  for (int mo = 0; mo < 8; ++mo){
    floatx4 bb = *reinterpret_cast<const floatx4a*>(&cmisc[128 + 16 * mo + 4 * g]);
    #pragma unroll
    for (int q = 0; q < 4; ++q){
      float v = acc2[mo][q] + bb[q];
      s1 += v; s2 += v * v;
    }
  }
  s1 += __shfl_xor(s1, 16); s2 += __shfl_xor(s2, 16);
  s1 += __shfl_xor(s1, 32); s2 += __shfl_xor(s2, 32);

  float mu   = s1 * (1.f / 128.f);
  float var  = s2 * (1.f / 128.f) - mu * mu;
  var = var > 0.f ? var : 0.f;
  float rstd = __builtin_amdgcn_rsqf(var + 1e-5f);

  float* op = out + (size_t)e0 * 128;
  #pragma unroll
  for (int mo = 0; mo < 8; ++mo){
    int c = 16 * mo + 4 * g;
    floatx4 bb = *reinterpret_cast<const floatx4a*>(&cmisc[128 + c]);
    floatx4 ls = *reinterpret_cast<const floatx4a*>(&cmisc[256 + c]);
    floatx4 lb = *reinterpret_cast<const floatx4a*>(&cmisc[384 + c]);
    uintx2a rv = *reinterpret_cast<const uintx2a*>(&tile[r * 64 + ((8 * mo + 2 * g) ^ sw8)]);
    floatx4 e4;
    e4[0] = __builtin_bit_cast(float, rv[0] << 16);
    e4[1] = __builtin_bit_cast(float, rv[0] & 0xffff0000u);
    e4[2] = __builtin_bit_cast(float, rv[1] << 16);
    e4[3] = __builtin_bit_cast(float, rv[1] & 0xffff0000u);
    floatx4 o4;
    #pragma unroll
    for (int q = 0; q < 4; ++q)
      o4[q] = (acc2[mo][q] + bb[q] - mu) * rstd * ls[q] + lb[q] + e4[q];
    *reinterpret_cast<floatx4a*>(op + c) = o4;
  }
}

extern "C" void kernel_launch(void* const* d_in, const int* in_sizes, int n_in,
                              void* d_out, int out_size, void* d_ws, size_t ws_size,
                              hipStream_t stream){
  const float* efeat = (const float*)d_in[0];
  const float* nfeat = (const float*)d_in[1];
  const int*   srci  = (const int*)d_in[2];
  const int*   dsti  = (const int*)d_in[3];
  const float* W1    = (const float*)d_in[4];
  const float* b1    = (const float*)d_in[5];
  const float* W2    = (const float*)d_in[6];
  const float* b2    = (const float*)d_in[7];
  const float* lns   = (const float*)d_in[8];
  const float* lnb   = (const float*)d_in[9];
  float* out = (float*)d_out;

  char* ws = (char*)d_ws;
  unsigned short* wall = (unsigned short*)ws;              // 131,072 B (8 swizzled windows)
  unsigned short* nfb  = (unsigned short*)(ws + 131072);   // 25,600,000 B

  prep_weights<<<(384 * 128 + 128 * 128) / 256, 256, 0, stream>>>(W1, W2, wall);
  prep_nfeat<<<2048, 256, 0, stream>>>(nfeat, (unsigned*)nfb, out + (size_t)E_N * 128);

  int blocks = E_N / 64;   // 9375, exact — no tail
  fused_edge<<<blocks, 256, 0, stream>>>(efeat, srci, dsti, nfb, wall,
                                         b1, b2, lns, lnb, out);
}